// Round 12
// baseline (216.130 us; speedup 1.0000x reference)
//
#include <hip/hip_runtime.h>
#include <math.h>

#define Dd 256
#define Tt 1024
#define Bb 32
#define Kk 1024
#define NROWS (Bb*Tt)            /* 32768 */
#define OUTQ  (Bb*Dd*Tt)         /* 8388608 */
#define SLACK 4e-4f
#define LIST_CAP 458752u         /* candidate list capacity (entries, 8B each) */
#define CANDB_CAP 1024u          /* per-block LDS candidate buffer */

typedef __bf16 b16x8 __attribute__((ext_vector_type(8)));
typedef float  f32x4 __attribute__((ext_vector_type(4)));

/* workspace layout (bytes) */
#define OFF_LOSS  0                      /* double                  */
#define OFF_GCNT  8                      /* u32 (memset with loss)  */
#define OFF_W2    256                    /* float[1024]             */
#define OFF_X2    8192                   /* float[32768]   128 KB   */
#define OFF_IDX   139264                 /* int[32768]     128 KB   */
#define OFF_PACK  270336                 /* u64[32768]     256 KB   */
#define OFF_GMINU 532480                 /* u32[32768]     128 KB (memset 0xFF with pack) */
#define OFF_LIST  663552                 /* uint2[448K]   3.5 MB    */
#define OFF_BT    4333568                /* bf16[1024*256] 512 KB   */
#define OFF_X     4857856                /* float[32768*256] 32 MB  */
#define OFF_A     38412288               /* bf16[32768*256]  16 MB  */
#define MIN_WS    (OFF_A + (size_t)NROWS*Dd*2)   /* 55,189,504 */

/* async global->LDS, 16B per lane, dest = wave-uniform base + lane*16 */
__device__ __forceinline__ void gload16(const void* g, void* l) {
    __builtin_amdgcn_global_load_lds(
        (const __attribute__((address_space(1))) void*)g,
        (__attribute__((address_space(3))) void*)l, 16, 0, 0);
}

/* order-preserving float<->uint map (works for negative f; distances f can
 * be negative since f = w2 - 2S excludes x2). min over mapped uints ==
 * exact min over floats, no fp arithmetic involved. */
__device__ __forceinline__ unsigned fmono(float f) {
    unsigned b = __float_as_uint(f);
    return b ^ ((unsigned)((int)b >> 31) | 0x80000000u);
}
__device__ __forceinline__ float fmono_inv(unsigned u) {
    unsigned b = (u & 0x80000000u) ? (u ^ 0x80000000u) : ~u;
    return __uint_as_float(b);
}

/* ---- w2[k]: numpy-pairwise fp32 sum of w*w (fallback path only) ---- */
__global__ void vq_w2(const float* __restrict__ cb, float* __restrict__ w2f) {
#pragma clang fp contract(off)
    const int k = blockIdx.x * 256 + threadIdx.x;
    if (k >= Kk) return;
    const float* w = cb + (size_t)k * Dd;
    float h[2];
    for (int half = 0; half < 2; ++half) {
        const float* p = w + half * 128;
        float r[8];
        for (int j = 0; j < 8; ++j) { float v = p[j]; r[j] = v * v; }
        for (int m = 1; m < 16; ++m)
            for (int j = 0; j < 8; ++j) { float v = p[m*8 + j]; r[j] += v * v; }
        h[half] = ((r[0]+r[1]) + (r[2]+r[3])) + ((r[4]+r[5]) + (r[6]+r[7]));
    }
    w2f[k] = h[0] + h[1];
}

/* ---- fused codebook prep: BT[c][k] = w_hi bf16  +  w2[c] ---- */
__global__ __launch_bounds__(256) void vq_cbprep(const float* __restrict__ cb,
                                                 float* __restrict__ w2f,
                                                 __bf16* __restrict__ BT) {
    __shared__ float wrow[256];
    const int c = blockIdx.x, t = threadIdx.x;          /* 1024 x 256 */
    float v = cb[(size_t)c*Dd + t];
    wrow[t] = v;
    BT[(size_t)c*Dd + t] = (__bf16)v;
    __syncthreads();
    if (t < 64) {
        float s = 0.0f;
        if (t < 16) {
#pragma clang fp contract(off)
            const int h = t >> 3, j = t & 7;
            float u = wrow[h*128 + j];
            float r8 = u * u;
            for (int m = 1; m < 16; ++m) {
                u = wrow[h*128 + m*8 + j];
                r8 += u * u;
            }
            s = r8;
        }
        s += __shfl_xor(s, 1, 64);
        s += __shfl_xor(s, 2, 64);
        s += __shfl_xor(s, 4, 64);
        s += __shfl_xor(s, 8, 64);
        if (t == 0) w2f[c] = s;
    }
}

/* ---- fused prep: latents -> X fp32 + A bf16 + x2 (exact numpy chain) ----
 * One block per 64 rows, all 256 dims as two 128-d halves in a [128][65]
 * LDS tile. x2: lane l4=(hh,jj) runs its 16-step pairwise chain on its own
 * half (partials in registers across halves), then the same 16-lane
 * butterfly tree as the proven vq_x2 -> bit-identical x2. (R9 bundled this
 * with a racy vmcnt schedule; R11 isolated that race -- this fusion is
 * sync-trivial: two uniform __syncthreads per half.)                    */
__global__ __launch_bounds__(256) void vq_prep_a(const float* __restrict__ lat,
                                                 float* __restrict__ X,
                                                 __bf16* __restrict__ A,
                                                 float* __restrict__ x2f) {
    __shared__ float tl[128][65];
    const int tid = threadIdx.x;
    const int rowbase = blockIdx.x * 64;                /* global row, mult of 64 */
    const int b = rowbase >> 10, t0 = rowbase & 1023;
    const int tt = tid & 63, sub = tid >> 6;
    const int wv = tid >> 6, l = tid & 63;
    const int g = l >> 4, l4 = l & 15, hh = l4 >> 3, jj = l4 & 7;
    const int dloc = tid & 127, trow2 = tid >> 7;

    float r8p[4];

    for (int half = 0; half < 2; ++half) {
        /* load 128 d x 64 t (coalesced) */
#pragma unroll
        for (int it = 0; it < 32; ++it) {
            int d = it*4 + sub;
            tl[d][tt] = lat[((size_t)(b*Dd + half*128 + d))*Tt + t0 + tt];
        }
        __syncthreads();
        /* transpose-write X and A rows for these 128 dims */
#pragma unroll
        for (int it = 0; it < 32; ++it) {
            int t = it*2 + trow2;
            float v = tl[dloc][t];
            size_t off = (size_t)(rowbase + t)*Dd + half*128 + dloc;
            X[off] = v;
            A[off] = (__bf16)v;
        }
        /* x2 partial: lanes whose hh == half run their exact chain */
#pragma unroll
        for (int pass = 0; pass < 4; ++pass) {
            int t = pass*16 + wv*4 + g;
            if (hh == half) {
#pragma clang fp contract(off)
                float v = tl[jj][t];
                float r8 = v * v;
                for (int m = 1; m < 16; ++m) {
                    v = tl[m*8 + jj][t];
                    r8 += v * v;
                }
                r8p[pass] = r8;
            }
        }
        __syncthreads();
    }
    /* butterfly per 16-lane group (identical tree to old vq_x2) */
#pragma unroll
    for (int pass = 0; pass < 4; ++pass) {
        float s = r8p[pass];
        s += __shfl_xor(s, 1, 64);
        s += __shfl_xor(s, 2, 64);
        s += __shfl_xor(s, 4, 64);
        s += __shfl_xor(s, 8, 64);
        if (l4 == 0) x2f[rowbase + pass*16 + wv*4 + g] = s;
    }
}

/* ---- filter GEMM + fused min/candidate epilogue ----
 * R6-proven config: 128x128 C-tile, 4 waves 2x2, 4x4 frags 16x16x32 bf16
 * MFMA, K=256, BK=64 double-buffer (2x32KB LDS), ONE __syncthreads per
 * K-step (implicit vmcnt(0) covers prefetch into the unused buffer), no
 * min-waves clause (R7/R8 spill lesson; R6 measured 88 VGPR, no spill).
 * Counted-vmcnt rotation (R11) was correct but SLOWER (81 vs 58) --
 * sched_barrier pinning defeats compiler scheduling (m141). Reverted.
 * Epilogue change vs R6: per-row slab-min goes to gminU[row] via
 * atomicMin on an order-preserving uint key (replaces rming + vq_gmin). */
__global__ __launch_bounds__(256) void vq_gemm(const __bf16* __restrict__ A,
                                               const __bf16* __restrict__ BT,
                                               const float* __restrict__ w2f,
                                               unsigned* __restrict__ gcnt,
                                               uint2* __restrict__ list,
                                               unsigned* __restrict__ gminU) {
    __shared__ __align__(16) char smem[65536];
    /* buf b @ b*32768: A 16KB [128][64], B 16KB @ +16384 */
    float (*rminS)[2] = (float(*)[2])smem;              /* 1 KB, overlay  */
    unsigned* nCand   = (unsigned*)(smem + 1024);
    unsigned* baseS   = (unsigned*)(smem + 1032);
    unsigned* candRC  = (unsigned*)(smem + 2048);       /* 4 KB            */
    float*    candF   = (float*)(smem + 6144);          /* 4 KB            */

    const int tid = threadIdx.x;
    const unsigned orig = blockIdx.x;
    const unsigned wgid = (orig & 7) * 256 + (orig >> 3);   /* XCD swizzle */
    const int bn = wgid & 7, bm = wgid >> 3;
    const int l = tid & 63, wv = tid >> 6;
    const int wm = (wv & 1) * 64, wn = (wv >> 1) * 64;
    const int m16 = l & 15, quad = l >> 4;

    f32x4 acc[4][4];
#pragma unroll
    for (int i = 0; i < 4; ++i)
#pragma unroll
        for (int j = 0; j < 4; ++j) acc[i][j] = (f32x4){0.f,0.f,0.f,0.f};

    const int r8  = l >> 3;             /* row within 8-row chunk */
    const int c8  = l & 7;              /* 16B chunk within 64-elem row */
    const int csw = ((c8 ^ r8) * 8);    /* swizzled source column (elements) */
    const int sw  = m16 & 7;            /* read-side row swizzle key */
    const size_t abase = (size_t)(bm*128) * Dd;
    const size_t bbase = (size_t)(bn*128) * Dd;

    auto stage = [&](int kt, int bsel) {
        char* dstA = smem + bsel*32768;
        char* dstB = smem + bsel*32768 + 16384;
        const int k0 = kt * 64;
#pragma unroll
        for (int p = 0; p < 4; ++p) {
            const int R0 = wv*32 + p*8;
            gload16(&A [abase + (size_t)(R0 + r8)*Dd + k0 + csw], dstA + R0*128);
            gload16(&BT[bbase + (size_t)(R0 + r8)*Dd + k0 + csw], dstB + R0*128);
        }
    };
    auto compute = [&](int bsel) {
        const char* As = smem + bsel*32768;
        const char* Bs = smem + bsel*32768 + 16384;
#pragma unroll
        for (int ks = 0; ks < 64; ks += 32) {
            const int k8 = ks >> 3;
            b16x8 a[4], b[4];
#pragma unroll
            for (int i = 0; i < 4; ++i)
                a[i] = *(const b16x8*)(As + (wm + 16*i + m16)*128 + (((k8 + quad) ^ sw) * 16));
#pragma unroll
            for (int j = 0; j < 4; ++j)
                b[j] = *(const b16x8*)(Bs + (wn + 16*j + m16)*128 + (((k8 + quad) ^ sw) * 16));
#pragma unroll
            for (int i = 0; i < 4; ++i)
#pragma unroll
                for (int j = 0; j < 4; ++j)
                    acc[i][j] = __builtin_amdgcn_mfma_f32_16x16x32_bf16(a[i], b[j], acc[i][j], 0, 0, 0);
        }
    };

    stage(0, 0);
    __syncthreads();
#pragma unroll
    for (int kt = 0; kt < 3; ++kt) {    /* K=256: 4 tiles of 64 */
        stage(kt + 1, (kt + 1) & 1);    /* prefetch next tile (unused buffer) */
        compute(kt & 1);                /* MFMA on current tile */
        __syncthreads();                /* drains vmcnt(0): prefetch landed  */
    }
    compute(1);                         /* tile 3 from buf1; buf0 now dead   */

    /* ---- epilogue: per-row slab-min + candidate append ---- */
    float w2n[4];
#pragma unroll
    for (int j = 0; j < 4; ++j) w2n[j] = w2f[bn*128 + wn + 16*j + m16];

    float vmin[4][4];
#pragma unroll
    for (int i = 0; i < 4; ++i)
#pragma unroll
        for (int g = 0; g < 4; ++g) {
            float v = w2n[0] - 2.0f * acc[i][0][g];
#pragma unroll
            for (int j = 1; j < 4; ++j)
                v = fminf(v, w2n[j] - 2.0f * acc[i][j][g]);
#pragma unroll
            for (int off = 1; off <= 8; off <<= 1)
                v = fminf(v, __shfl_xor(v, off, 64));   /* min over m16 group */
            vmin[i][g] = v;
        }
    if (m16 == 0) {
#pragma unroll
        for (int i = 0; i < 4; ++i)
#pragma unroll
            for (int g = 0; g < 4; ++g)
                rminS[wm + 16*i + quad*4 + g][wn >> 6] = vmin[i][g];
    }
    if (tid == 0) *nCand = 0u;
    __syncthreads();
    if (tid < 128)                                   /* per-row slab-min -> global */
        atomicMin(&gminU[bm*128 + tid], fmono(fminf(rminS[tid][0], rminS[tid][1])));
#pragma unroll
    for (int i = 0; i < 4; ++i)
#pragma unroll
        for (int g = 0; g < 4; ++g) {
            const int rloc = wm + 16*i + quad*4 + g;
            const float thr = fminf(rminS[rloc][0], rminS[rloc][1]) + SLACK;
#pragma unroll
            for (int j = 0; j < 4; ++j) {
                float f = w2n[j] - 2.0f * acc[i][j][g];
                if (f <= thr) {
                    unsigned slot = atomicAdd(nCand, 1u);
                    if (slot < CANDB_CAP) {
                        candRC[slot] = ((unsigned)(bm*128 + rloc) << 10)
                                     | (unsigned)(bn*128 + wn + 16*j + m16);
                        candF[slot]  = f;
                    }
                }
            }
        }
    __syncthreads();
    unsigned nc = *nCand; if (nc > CANDB_CAP) nc = CANDB_CAP;
    if (tid == 0) *baseS = atomicAdd(gcnt, nc);
    __syncthreads();
    const unsigned base = *baseS;
    for (unsigned i = tid; i < nc; i += 256) {
        unsigned dst = base + i;
        if (dst < LIST_CAP) {
            uint2 e; e.x = candRC[i]; e.y = __float_as_uint(candF[i]);
            list[dst] = e;
        }
    }
}

/* ---- rescore: dense worklist, ONE candidate per lane; global pre-filter
 * f <= gmin+SLACK (gmin from gminU via exact inverse map) kills ~7/8 of
 * entries before touching X/cb. Survivors: bit-exact numpy fp32 chain,
 * merged per row via lexicographic-(dv, code) u64 atomicMin.           ---- */
__global__ __launch_bounds__(256) void vq_rescore(const float* __restrict__ X,
                                                  const float* __restrict__ cb,
                                                  const float* __restrict__ w2f,
                                                  const float* __restrict__ x2f,
                                                  const unsigned* __restrict__ gminU,
                                                  const unsigned* __restrict__ gcnt,
                                                  const uint2* __restrict__ list,
                                                  unsigned long long* __restrict__ pack) {
    unsigned n = *gcnt; if (n > LIST_CAP) n = LIST_CAP;
    const unsigned stride = gridDim.x * 256u;
    for (unsigned i = blockIdx.x * 256u + threadIdx.x; i < n; i += stride) {
        const uint2 e = list[i];
        const int row = (int)(e.x >> 10);
        const int c   = (int)(e.x & 1023u);
        const float gm = fmono_inv(gminU[row]);
        if (__uint_as_float(e.y) > gm + SLACK) continue;  /* global SLACK filter */

        const float4* wq = (const float4*)(cb + (size_t)c * Dd);
        const float4* xq = (const float4*)(X + (size_t)row * Dd);
        float acc = 0.0f;
#pragma unroll 8
        for (int m = 0; m < 64; ++m) {              /* strict k-ascending fp32 chain */
            float4 xa = xq[m], wa = wq[m];
            acc = __builtin_fmaf(xa.x, wa.x, acc);
            acc = __builtin_fmaf(xa.y, wa.y, acc);
            acc = __builtin_fmaf(xa.z, wa.z, acc);
            acc = __builtin_fmaf(xa.w, wa.w, acc);
        }
        float t2 = x2f[row] - 2.0f * acc;           /* fl(x2 - fl(2M)), 2*acc exact */
        float dv = t2 + w2f[c];                     /* fl(.. + w2)                  */
        unsigned long long pk = ((unsigned long long)__float_as_uint(dv) << 32)
                              | (unsigned long long)(unsigned)c;
        atomicMin(&pack[row], pk);
    }
}

/* ---- pick: unpack per-row winner -> idx (int + float out) + loss sum ---- */
__global__ __launch_bounds__(256) void vq_pick(const unsigned long long* __restrict__ pack,
                                               int* __restrict__ idx,
                                               float* __restrict__ out,
                                               double* __restrict__ loss_acc) {
    __shared__ double wsum[4];
    const int tid = threadIdx.x;
    const int row = blockIdx.x * 256 + tid;
    const unsigned long long pk = pack[row];
    const int cc = (int)(pk & 0xFFFFFFFFull);
    idx[row] = cc;
    out[OUTQ + 1 + row] = (float)cc;
    double d = (double)__uint_as_float((unsigned)(pk >> 32));
    for (int off = 32; off; off >>= 1) d += __shfl_xor(d, off, 64);
    if ((tid & 63) == 0) wsum[tid >> 6] = d;
    __syncthreads();
    if (tid == 0) atomicAdd(loss_acc, wsum[0] + wsum[1] + wsum[2] + wsum[3]);
}

/* ---- R5 fallback main (s_load path), used only if ws too small ---- */
typedef float float8_t __attribute__((ext_vector_type(8)));
__global__ __launch_bounds__(512) void vq_main(const float* __restrict__ latents,
                                               const float* __restrict__ cb,
                                               const float* __restrict__ w2f,
                                               int* __restrict__ idx,
                                               double* __restrict__ loss_acc) {
    __shared__ float  xs[Dd*64];
    __shared__ float  x2f[64];
    __shared__ float  bsd[8*64];
    __shared__ int    bci[8*64];
    __shared__ double red[64];
    const int tid = threadIdx.x;
    const int rr  = tid & 63;
    const int dg  = tid >> 6;
    const int blk = blockIdx.x;
    const int bb  = blk >> 4;
    const int t0  = (blk & 15) << 6;
    const float* lat = latents + (size_t)bb * Dd * Tt + t0;
    for (int d = dg; d < Dd; d += 8) xs[d*64 + rr] = lat[(size_t)d * Tt + rr];
    __syncthreads();
    if (tid < 64) {
#pragma clang fp contract(off)
        float h[2];
        for (int half = 0; half < 2; ++half) {
            float r[8];
            for (int j = 0; j < 8; ++j) { float v = xs[(half*128 + j)*64 + tid]; r[j] = v*v; }
            for (int m = 1; m < 16; ++m)
                for (int j = 0; j < 8; ++j) { float v = xs[(half*128 + m*8 + j)*64 + tid]; r[j] += v*v; }
            h[half] = ((r[0]+r[1]) + (r[2]+r[3])) + ((r[4]+r[5]) + (r[6]+r[7]));
        }
        x2f[tid] = h[0] + h[1];
    }
    __syncthreads();
    const int slab = __builtin_amdgcn_readfirstlane(tid >> 6);
    const int lane = tid & 63;
    const float x2r = x2f[lane];
    const float* wq = cb + (size_t)slab * 128 * Dd;
    float best = 3.4e38f; int bestc = 0;
    for (int cg = 0; cg < 16; ++cg) {
        const int c0 = cg * 8;
        float acc[8];
#pragma unroll
        for (int g = 0; g < 8; ++g) acc[g] = 0.0f;
        for (int kc = 0; kc < 32; ++kc) {
            float8_t w8[8];
#pragma unroll
            for (int g = 0; g < 8; ++g) w8[g] = *(const float8_t*)(wq + (size_t)(c0+g)*Dd + kc*8);
            float xk[8];
#pragma unroll
            for (int j = 0; j < 8; ++j) xk[j] = xs[(kc*8 + j)*64 + lane];
#pragma unroll
            for (int g = 0; g < 8; ++g)
#pragma unroll
                for (int j = 0; j < 8; ++j) acc[g] = __builtin_fmaf(xk[j], w8[g][j], acc[g]);
        }
#pragma unroll
        for (int g = 0; g < 8; ++g) {
            float t2 = x2r - 2.0f * acc[g];
            float dvv = t2 + w2f[slab*128 + c0 + g];
            if (dvv < best) { best = dvv; bestc = slab*128 + c0 + g; }
        }
    }
    bsd[slab*64 + lane] = best; bci[slab*64 + lane] = bestc;
    __syncthreads();
    if (tid < 64) {
        float b0 = bsd[tid]; int ci = bci[tid];
#pragma unroll
        for (int s = 1; s < 8; ++s) { float b1 = bsd[s*64 + tid]; if (b1 < b0) { b0 = b1; ci = bci[s*64 + tid]; } }
        idx[blk*64 + tid] = ci; red[tid] = (double)b0;
    }
    __syncthreads();
    if (tid == 0) { double s = 0.0; for (int i = 0; i < 64; ++i) s += red[i]; atomicAdd(loss_acc, s); }
}

/* ---- gather: out[b][d][t] = cb[idx[b*T+t]][d] ---- */
__global__ void vq_gather(const float* __restrict__ cb,
                          const int* __restrict__ idx,
                          float* __restrict__ out) {
    const size_t g = (size_t)blockIdx.x * 256 + threadIdx.x;
    const int t  = (int)(g & 1023);
    const int d4 = (int)((g >> 10) & 63);
    const int b  = (int)(g >> 16);
    const int i  = idx[b*Tt + t];
    const float4 w4 = *(const float4*)(cb + (size_t)i*Dd + d4*4);
    float* o = out + ((size_t)(b*Dd + d4*4)) * Tt + t;
    o[0]    = w4.x;
    o[Tt]   = w4.y;
    o[2*Tt] = w4.z;
    o[3*Tt] = w4.w;
}

/* ---- finalize (loss only; pick wrote float indices) ---- */
__global__ void vq_finalize(const double* __restrict__ loss_acc,
                            float* __restrict__ out) {
    out[OUTQ] = (float)(1.25 * loss_acc[0] / (double)OUTQ);
}

/* ---- fallback index->float (vq_main path only) ---- */
__global__ void vq_idxf(const int* __restrict__ idx, float* __restrict__ out) {
    const int r = blockIdx.x * 256 + threadIdx.x;
    if (r < NROWS) out[OUTQ + 1 + r] = (float)idx[r];
}

extern "C" void kernel_launch(void* const* d_in, const int* in_sizes, int n_in,
                              void* d_out, int out_size, void* d_ws, size_t ws_size,
                              hipStream_t stream) {
    const float* latents = (const float*)d_in[0];
    const float* cb      = (const float*)d_in[1];
    float* out = (float*)d_out;
    char*  ws  = (char*)d_ws;

    double* loss = (double*)(ws + OFF_LOSS);
    float*  w2f  = (float*)(ws + OFF_W2);
    int*    idx  = (int*)(ws + OFF_IDX);

    hipMemsetAsync(ws, 0, 16, stream);                 /* loss + gcnt */

    if (ws_size >= (size_t)MIN_WS) {
        unsigned*           gcnt  = (unsigned*)(ws + OFF_GCNT);
        float*              x2f   = (float*)(ws + OFF_X2);
        unsigned long long* pack  = (unsigned long long*)(ws + OFF_PACK);
        unsigned*           gminU = (unsigned*)(ws + OFF_GMINU);
        uint2*              list  = (uint2*)(ws + OFF_LIST);
        __bf16*             BT    = (__bf16*)(ws + OFF_BT);
        float*              X     = (float*)(ws + OFF_X);
        __bf16*             A     = (__bf16*)(ws + OFF_A);

        /* pack (256KB) + gminU (128KB) contiguous: one 0xFF memset */
        hipMemsetAsync(pack, 0xFF, 393216, stream);
        vq_cbprep<<<Kk, 256, 0, stream>>>(cb, w2f, BT);
        vq_prep_a<<<NROWS/64, 256, 0, stream>>>(latents, X, A, x2f);
        vq_gemm<<<2048, 256, 0, stream>>>(A, BT, w2f, gcnt, list, gminU);
        vq_rescore<<<1024, 256, 0, stream>>>(X, cb, w2f, x2f, gminU, gcnt, list, pack);
        vq_pick<<<NROWS/256, 256, 0, stream>>>(pack, idx, out, loss);
    } else {
        vq_w2<<<4, 256, 0, stream>>>(cb, w2f);
        vq_main<<<NROWS/64, 512, 0, stream>>>(latents, cb, w2f, idx, loss);
        vq_idxf<<<(NROWS + 255)/256, 256, 0, stream>>>(idx, out);
    }

    vq_gather<<<(Bb*(Dd/4)*Tt)/256, 256, 0, stream>>>(cb, idx, out);
    vq_finalize<<<1, 1, 0, stream>>>(loss, out);
}

// Round 13
// 194.968 us; speedup vs baseline: 1.1085x; 1.1085x over previous
//
#include <hip/hip_runtime.h>
#include <math.h>

#define Dd 256
#define Tt 1024
#define Bb 32
#define Kk 1024
#define NROWS (Bb*Tt)            /* 32768 */
#define OUTQ  (Bb*Dd*Tt)         /* 8388608 */
#define SLACK 4e-4f
#define LIST_CAP 458752u         /* candidate list capacity (entries, 8B each) */
#define CANDB_CAP 1024u          /* per-block LDS candidate buffer */

typedef __bf16 b16x8 __attribute__((ext_vector_type(8)));
typedef float  f32x4 __attribute__((ext_vector_type(4)));

/* workspace layout (bytes) */
#define OFF_LOSS  0                      /* double                  */
#define OFF_GCNT  8                      /* u32                     */
#define OFF_DONE  12                     /* u32                     */
#define OFF_W2    256                    /* float[1024]             */
#define OFF_X2    8192                   /* float[32768]   128 KB   */
#define OFF_IDX   139264                 /* int[32768]     128 KB   */
#define OFF_PACK  270336                 /* u64[32768]     256 KB   */
#define OFF_GMINU 532480                 /* u32[32768]     128 KB   */
#define OFF_LIST  663552                 /* uint2[448K]   3.5 MB    */
#define OFF_BT    4333568                /* bf16[1024*256] 512 KB   */
#define OFF_X     4857856                /* float[32768*256] 32 MB  */
#define OFF_A     38412288               /* bf16[32768*256]  16 MB  */
#define MIN_WS    (OFF_A + (size_t)NROWS*Dd*2)   /* 55,189,504 */

/* async global->LDS, 16B per lane, dest = wave-uniform base + lane*16 */
__device__ __forceinline__ void gload16(const void* g, void* l) {
    __builtin_amdgcn_global_load_lds(
        (const __attribute__((address_space(1))) void*)g,
        (__attribute__((address_space(3))) void*)l, 16, 0, 0);
}

/* order-preserving float<->uint map (valid for negative f; f = w2 - 2S can
 * be negative). min over mapped uints == exact min over floats. */
__device__ __forceinline__ unsigned fmono(float f) {
    unsigned b = __float_as_uint(f);
    return b ^ ((unsigned)((int)b >> 31) | 0x80000000u);
}
__device__ __forceinline__ float fmono_inv(unsigned u) {
    unsigned b = (u & 0x80000000u) ? (u ^ 0x80000000u) : ~u;
    return __uint_as_float(b);
}

/* ---- w2[k]: numpy-pairwise fp32 sum of w*w (fallback path only) ---- */
__global__ void vq_w2(const float* __restrict__ cb, float* __restrict__ w2f) {
#pragma clang fp contract(off)
    const int k = blockIdx.x * 256 + threadIdx.x;
    if (k >= Kk) return;
    const float* w = cb + (size_t)k * Dd;
    float h[2];
    for (int half = 0; half < 2; ++half) {
        const float* p = w + half * 128;
        float r[8];
        for (int j = 0; j < 8; ++j) { float v = p[j]; r[j] = v * v; }
        for (int m = 1; m < 16; ++m)
            for (int j = 0; j < 8; ++j) { float v = p[m*8 + j]; r[j] += v * v; }
        h[half] = ((r[0]+r[1]) + (r[2]+r[3])) + ((r[4]+r[5]) + (r[6]+r[7]));
    }
    w2f[k] = h[0] + h[1];
}

/* ---- fused codebook prep: BT[c][k] = w_hi bf16 + w2[c]; block0 also
 * zeroes loss/gcnt/done (replaces a memset launch; runs first in stream). */
__global__ __launch_bounds__(256) void vq_cbprep(const float* __restrict__ cb,
                                                 float* __restrict__ w2f,
                                                 __bf16* __restrict__ BT,
                                                 double* __restrict__ loss,
                                                 unsigned* __restrict__ gcnt,
                                                 unsigned* __restrict__ done) {
    __shared__ float wrow[256];
    const int c = blockIdx.x, t = threadIdx.x;          /* 1024 x 256 */
    if (c == 0 && t == 0) { *loss = 0.0; *gcnt = 0u; *done = 0u; }
    float v = cb[(size_t)c*Dd + t];
    wrow[t] = v;
    BT[(size_t)c*Dd + t] = (__bf16)v;
    __syncthreads();
    if (t < 64) {
        float s = 0.0f;
        if (t < 16) {
#pragma clang fp contract(off)
            const int h = t >> 3, j = t & 7;
            float u = wrow[h*128 + j];
            float r8 = u * u;
            for (int m = 1; m < 16; ++m) {
                u = wrow[h*128 + m*8 + j];
                r8 += u * u;
            }
            s = r8;
        }
        s += __shfl_xor(s, 1, 64);
        s += __shfl_xor(s, 2, 64);
        s += __shfl_xor(s, 4, 64);
        s += __shfl_xor(s, 8, 64);
        if (t == 0) w2f[c] = s;
    }
}

/* ---- transpose latents -> X[r][d] fp32 + A[r][d] bf16 (hi only) ----
 * R10-proven 2048-block streaming version (R12's 512-block fused variant
 * cost ~+15us: 2 blocks/CU, serialized halves). blockIdx.y==0 blocks also
 * init pack/gminU for their 64 rows (replaces the 384KB memset launch). */
__global__ void vq_prep_a(const float* __restrict__ lat, float* __restrict__ X,
                          __bf16* __restrict__ A,
                          unsigned long long* __restrict__ pack,
                          unsigned* __restrict__ gminU) {
    __shared__ float tl[64][65];
    const int tid = threadIdx.x;
    const int rowbase = blockIdx.x * 64;                /* global row, mult of 64 */
    const int b = rowbase >> 10, t0 = rowbase & 1023;
    const int d0 = blockIdx.y * 64;
    const int tt = tid & 63, sub = tid >> 6;
    if (blockIdx.y == 0 && tid < 64) {
        pack [rowbase + tid] = ~0ull;
        gminU[rowbase + tid] = 0xFFFFFFFFu;
    }
#pragma unroll
    for (int it = 0; it < 16; ++it) {
        int d = it*4 + sub;
        tl[d][tt] = lat[((size_t)(b*Dd + d0 + d))*Tt + t0 + tt];
    }
    __syncthreads();
    const int dd = tid & 63;
#pragma unroll
    for (int it = 0; it < 16; ++it) {
        int t = it*4 + sub;
        float v = tl[dd][t];
        int grow = rowbase + t;
        X[(size_t)grow*Dd + d0 + dd] = v;
        A[(size_t)grow*Dd + d0 + dd] = (__bf16)v;
    }
}

/* ---- x2[r]: exact numpy-pairwise ||x||^2 per row (R10-proven) ---- */
__global__ __launch_bounds__(256) void vq_x2(const float* __restrict__ X,
                                             float* __restrict__ x2f) {
    __shared__ float xrow[4][256];
    const int tid = threadIdx.x;
    const int wv = tid >> 6, l = tid & 63;
    const int row = blockIdx.x * 4 + wv;

    const float4* xg = (const float4*)(X + (size_t)row * Dd);
    *(float4*)&xrow[wv][l*4] = xg[l];
    __syncthreads();

    float s = 0.0f;
    if (l < 16) {
#pragma clang fp contract(off)
        const int h = l >> 3, j = l & 7;
        float v = xrow[wv][h*128 + j];
        float r8 = v * v;
        for (int m = 1; m < 16; ++m) {
            v = xrow[wv][h*128 + m*8 + j];
            r8 += v * v;
        }
        s = r8;
    }
    s += __shfl_xor(s, 1, 64);
    s += __shfl_xor(s, 2, 64);
    s += __shfl_xor(s, 4, 64);
    s += __shfl_xor(s, 8, 64);          /* == numpy pairwise combine (commutative) */
    if (l == 0) x2f[row] = s;
}

/* ---- filter GEMM + fused min/candidate epilogue (R12-proven, 57us) ----
 * 128x128 C-tile, 4 waves 2x2, 4x4 frags 16x16x32 bf16 MFMA, K=256,
 * BK=64 double-buffer (2x32KB LDS), ONE __syncthreads per K-step, no
 * min-waves clause (R7/R8 spill lesson). Per-row slab-min -> gminU via
 * atomicMin on order-preserving uint key.                               */
__global__ __launch_bounds__(256) void vq_gemm(const __bf16* __restrict__ A,
                                               const __bf16* __restrict__ BT,
                                               const float* __restrict__ w2f,
                                               unsigned* __restrict__ gcnt,
                                               uint2* __restrict__ list,
                                               unsigned* __restrict__ gminU) {
    __shared__ __align__(16) char smem[65536];
    /* buf b @ b*32768: A 16KB [128][64], B 16KB @ +16384 */
    float (*rminS)[2] = (float(*)[2])smem;              /* 1 KB, overlay  */
    unsigned* nCand   = (unsigned*)(smem + 1024);
    unsigned* baseS   = (unsigned*)(smem + 1032);
    unsigned* candRC  = (unsigned*)(smem + 2048);       /* 4 KB            */
    float*    candF   = (float*)(smem + 6144);          /* 4 KB            */

    const int tid = threadIdx.x;
    const unsigned orig = blockIdx.x;
    const unsigned wgid = (orig & 7) * 256 + (orig >> 3);   /* XCD swizzle */
    const int bn = wgid & 7, bm = wgid >> 3;
    const int l = tid & 63, wv = tid >> 6;
    const int wm = (wv & 1) * 64, wn = (wv >> 1) * 64;
    const int m16 = l & 15, quad = l >> 4;

    f32x4 acc[4][4];
#pragma unroll
    for (int i = 0; i < 4; ++i)
#pragma unroll
        for (int j = 0; j < 4; ++j) acc[i][j] = (f32x4){0.f,0.f,0.f,0.f};

    const int r8  = l >> 3;             /* row within 8-row chunk */
    const int c8  = l & 7;              /* 16B chunk within 64-elem row */
    const int csw = ((c8 ^ r8) * 8);    /* swizzled source column (elements) */
    const int sw  = m16 & 7;            /* read-side row swizzle key */
    const size_t abase = (size_t)(bm*128) * Dd;
    const size_t bbase = (size_t)(bn*128) * Dd;

    auto stage = [&](int kt, int bsel) {
        char* dstA = smem + bsel*32768;
        char* dstB = smem + bsel*32768 + 16384;
        const int k0 = kt * 64;
#pragma unroll
        for (int p = 0; p < 4; ++p) {
            const int R0 = wv*32 + p*8;
            gload16(&A [abase + (size_t)(R0 + r8)*Dd + k0 + csw], dstA + R0*128);
            gload16(&BT[bbase + (size_t)(R0 + r8)*Dd + k0 + csw], dstB + R0*128);
        }
    };
    auto compute = [&](int bsel) {
        const char* As = smem + bsel*32768;
        const char* Bs = smem + bsel*32768 + 16384;
#pragma unroll
        for (int ks = 0; ks < 64; ks += 32) {
            const int k8 = ks >> 3;
            b16x8 a[4], b[4];
#pragma unroll
            for (int i = 0; i < 4; ++i)
                a[i] = *(const b16x8*)(As + (wm + 16*i + m16)*128 + (((k8 + quad) ^ sw) * 16));
#pragma unroll
            for (int j = 0; j < 4; ++j)
                b[j] = *(const b16x8*)(Bs + (wn + 16*j + m16)*128 + (((k8 + quad) ^ sw) * 16));
#pragma unroll
            for (int i = 0; i < 4; ++i)
#pragma unroll
                for (int j = 0; j < 4; ++j)
                    acc[i][j] = __builtin_amdgcn_mfma_f32_16x16x32_bf16(a[i], b[j], acc[i][j], 0, 0, 0);
        }
    };

    stage(0, 0);
    __syncthreads();
#pragma unroll
    for (int kt = 0; kt < 3; ++kt) {    /* K=256: 4 tiles of 64 */
        stage(kt + 1, (kt + 1) & 1);    /* prefetch next tile (unused buffer) */
        compute(kt & 1);                /* MFMA on current tile */
        __syncthreads();                /* drains vmcnt(0): prefetch landed  */
    }
    compute(1);                         /* tile 3 from buf1; buf0 now dead   */

    /* ---- epilogue: per-row slab-min + candidate append ---- */
    float w2n[4];
#pragma unroll
    for (int j = 0; j < 4; ++j) w2n[j] = w2f[bn*128 + wn + 16*j + m16];

    float vmin[4][4];
#pragma unroll
    for (int i = 0; i < 4; ++i)
#pragma unroll
        for (int g = 0; g < 4; ++g) {
            float v = w2n[0] - 2.0f * acc[i][0][g];
#pragma unroll
            for (int j = 1; j < 4; ++j)
                v = fminf(v, w2n[j] - 2.0f * acc[i][j][g]);
#pragma unroll
            for (int off = 1; off <= 8; off <<= 1)
                v = fminf(v, __shfl_xor(v, off, 64));   /* min over m16 group */
            vmin[i][g] = v;
        }
    if (m16 == 0) {
#pragma unroll
        for (int i = 0; i < 4; ++i)
#pragma unroll
            for (int g = 0; g < 4; ++g)
                rminS[wm + 16*i + quad*4 + g][wn >> 6] = vmin[i][g];
    }
    if (tid == 0) *nCand = 0u;
    __syncthreads();
    if (tid < 128)                                   /* per-row slab-min -> global */
        atomicMin(&gminU[bm*128 + tid], fmono(fminf(rminS[tid][0], rminS[tid][1])));
#pragma unroll
    for (int i = 0; i < 4; ++i)
#pragma unroll
        for (int g = 0; g < 4; ++g) {
            const int rloc = wm + 16*i + quad*4 + g;
            const float thr = fminf(rminS[rloc][0], rminS[rloc][1]) + SLACK;
#pragma unroll
            for (int j = 0; j < 4; ++j) {
                float f = w2n[j] - 2.0f * acc[i][j][g];
                if (f <= thr) {
                    unsigned slot = atomicAdd(nCand, 1u);
                    if (slot < CANDB_CAP) {
                        candRC[slot] = ((unsigned)(bm*128 + rloc) << 10)
                                     | (unsigned)(bn*128 + wn + 16*j + m16);
                        candF[slot]  = f;
                    }
                }
            }
        }
    __syncthreads();
    unsigned nc = *nCand; if (nc > CANDB_CAP) nc = CANDB_CAP;
    if (tid == 0) *baseS = atomicAdd(gcnt, nc);
    __syncthreads();
    const unsigned base = *baseS;
    for (unsigned i = tid; i < nc; i += 256) {
        unsigned dst = base + i;
        if (dst < LIST_CAP) {
            uint2 e; e.x = candRC[i]; e.y = __float_as_uint(candF[i]);
            list[dst] = e;
        }
    }
}

/* ---- rescore: dense worklist, ONE candidate per lane; global pre-filter
 * f <= gmin+SLACK kills ~7/8 of entries before touching X/cb. Survivors:
 * bit-exact numpy fp32 chain, merged per row via lexicographic-(dv, code)
 * u64 atomicMin.                                                       ---- */
__global__ __launch_bounds__(256) void vq_rescore(const float* __restrict__ X,
                                                  const float* __restrict__ cb,
                                                  const float* __restrict__ w2f,
                                                  const float* __restrict__ x2f,
                                                  const unsigned* __restrict__ gminU,
                                                  const unsigned* __restrict__ gcnt,
                                                  const uint2* __restrict__ list,
                                                  unsigned long long* __restrict__ pack) {
    unsigned n = *gcnt; if (n > LIST_CAP) n = LIST_CAP;
    const unsigned stride = gridDim.x * 256u;
    for (unsigned i = blockIdx.x * 256u + threadIdx.x; i < n; i += stride) {
        const uint2 e = list[i];
        const int row = (int)(e.x >> 10);
        const int c   = (int)(e.x & 1023u);
        const float gm = fmono_inv(gminU[row]);
        if (__uint_as_float(e.y) > gm + SLACK) continue;  /* global SLACK filter */

        const float4* wq = (const float4*)(cb + (size_t)c * Dd);
        const float4* xq = (const float4*)(X + (size_t)row * Dd);
        float acc = 0.0f;
#pragma unroll 8
        for (int m = 0; m < 64; ++m) {              /* strict k-ascending fp32 chain */
            float4 xa = xq[m], wa = wq[m];
            acc = __builtin_fmaf(xa.x, wa.x, acc);
            acc = __builtin_fmaf(xa.y, wa.y, acc);
            acc = __builtin_fmaf(xa.z, wa.z, acc);
            acc = __builtin_fmaf(xa.w, wa.w, acc);
        }
        float t2 = x2f[row] - 2.0f * acc;           /* fl(x2 - fl(2M)), 2*acc exact */
        float dv = t2 + w2f[c];                     /* fl(.. + w2)                  */
        unsigned long long pk = ((unsigned long long)__float_as_uint(dv) << 32)
                              | (unsigned long long)(unsigned)c;
        atomicMin(&pack[row], pk);
    }
}

/* ---- pick: per-row winner -> idx + float out + loss; last-done block
 * writes the final loss scalar (replaces vq_finalize launch). Device-scope
 * atomics + threadfence make this XCD-safe; coherent read of the final
 * double via atomicAdd(loss, 0.0).                                     ---- */
__global__ __launch_bounds__(256) void vq_pick(const unsigned long long* __restrict__ pack,
                                               int* __restrict__ idx,
                                               float* __restrict__ out,
                                               double* __restrict__ loss_acc,
                                               unsigned* __restrict__ done) {
    __shared__ double wsum[4];
    const int tid = threadIdx.x;
    const int row = blockIdx.x * 256 + tid;
    const unsigned long long pk = pack[row];
    const int cc = (int)(pk & 0xFFFFFFFFull);
    idx[row] = cc;
    out[OUTQ + 1 + row] = (float)cc;
    double d = (double)__uint_as_float((unsigned)(pk >> 32));
    for (int off = 32; off; off >>= 1) d += __shfl_xor(d, off, 64);
    if ((tid & 63) == 0) wsum[tid >> 6] = d;
    __syncthreads();
    if (tid == 0) {
        atomicAdd(loss_acc, wsum[0] + wsum[1] + wsum[2] + wsum[3]);
        __threadfence();
        unsigned prev = atomicAdd(done, 1u);
        if (prev == gridDim.x - 1) {
            double total = atomicAdd(loss_acc, 0.0);    /* coherent final read */
            out[OUTQ] = (float)(1.25 * total / (double)OUTQ);
        }
    }
}

/* ---- R5 fallback main (s_load path), used only if ws too small ---- */
typedef float float8_t __attribute__((ext_vector_type(8)));
__global__ __launch_bounds__(512) void vq_main(const float* __restrict__ latents,
                                               const float* __restrict__ cb,
                                               const float* __restrict__ w2f,
                                               int* __restrict__ idx,
                                               double* __restrict__ loss_acc) {
    __shared__ float  xs[Dd*64];
    __shared__ float  x2f[64];
    __shared__ float  bsd[8*64];
    __shared__ int    bci[8*64];
    __shared__ double red[64];
    const int tid = threadIdx.x;
    const int rr  = tid & 63;
    const int dg  = tid >> 6;
    const int blk = blockIdx.x;
    const int bb  = blk >> 4;
    const int t0  = (blk & 15) << 6;
    const float* lat = latents + (size_t)bb * Dd * Tt + t0;
    for (int d = dg; d < Dd; d += 8) xs[d*64 + rr] = lat[(size_t)d * Tt + rr];
    __syncthreads();
    if (tid < 64) {
#pragma clang fp contract(off)
        float h[2];
        for (int half = 0; half < 2; ++half) {
            float r[8];
            for (int j = 0; j < 8; ++j) { float v = xs[(half*128 + j)*64 + tid]; r[j] = v*v; }
            for (int m = 1; m < 16; ++m)
                for (int j = 0; j < 8; ++j) { float v = xs[(half*128 + m*8 + j)*64 + tid]; r[j] += v*v; }
            h[half] = ((r[0]+r[1]) + (r[2]+r[3])) + ((r[4]+r[5]) + (r[6]+r[7]));
        }
        x2f[tid] = h[0] + h[1];
    }
    __syncthreads();
    const int slab = __builtin_amdgcn_readfirstlane(tid >> 6);
    const int lane = tid & 63;
    const float x2r = x2f[lane];
    const float* wq = cb + (size_t)slab * 128 * Dd;
    float best = 3.4e38f; int bestc = 0;
    for (int cg = 0; cg < 16; ++cg) {
        const int c0 = cg * 8;
        float acc[8];
#pragma unroll
        for (int g = 0; g < 8; ++g) acc[g] = 0.0f;
        for (int kc = 0; kc < 32; ++kc) {
            float8_t w8[8];
#pragma unroll
            for (int g = 0; g < 8; ++g) w8[g] = *(const float8_t*)(wq + (size_t)(c0+g)*Dd + kc*8);
            float xk[8];
#pragma unroll
            for (int j = 0; j < 8; ++j) xk[j] = xs[(kc*8 + j)*64 + lane];
#pragma unroll
            for (int g = 0; g < 8; ++g)
#pragma unroll
                for (int j = 0; j < 8; ++j) acc[g] = __builtin_fmaf(xk[j], w8[g][j], acc[g]);
        }
#pragma unroll
        for (int g = 0; g < 8; ++g) {
            float t2 = x2r - 2.0f * acc[g];
            float dvv = t2 + w2f[slab*128 + c0 + g];
            if (dvv < best) { best = dvv; bestc = slab*128 + c0 + g; }
        }
    }
    bsd[slab*64 + lane] = best; bci[slab*64 + lane] = bestc;
    __syncthreads();
    if (tid < 64) {
        float b0 = bsd[tid]; int ci = bci[tid];
#pragma unroll
        for (int s = 1; s < 8; ++s) { float b1 = bsd[s*64 + tid]; if (b1 < b0) { b0 = b1; ci = bci[s*64 + tid]; } }
        idx[blk*64 + tid] = ci; red[tid] = (double)b0;
    }
    __syncthreads();
    if (tid == 0) { double s = 0.0; for (int i = 0; i < 64; ++i) s += red[i]; atomicAdd(loss_acc, s); }
}

/* ---- gather: out[b][d][t] = cb[idx[b*T+t]][d] ---- */
__global__ void vq_gather(const float* __restrict__ cb,
                          const int* __restrict__ idx,
                          float* __restrict__ out) {
    const size_t g = (size_t)blockIdx.x * 256 + threadIdx.x;
    const int t  = (int)(g & 1023);
    const int d4 = (int)((g >> 10) & 63);
    const int b  = (int)(g >> 16);
    const int i  = idx[b*Tt + t];
    const float4 w4 = *(const float4*)(cb + (size_t)i*Dd + d4*4);
    float* o = out + ((size_t)(b*Dd + d4*4)) * Tt + t;
    o[0]    = w4.x;
    o[Tt]   = w4.y;
    o[2*Tt] = w4.z;
    o[3*Tt] = w4.w;
}

/* ---- finalize (fallback path only) ---- */
__global__ void vq_finalize(const double* __restrict__ loss_acc,
                            float* __restrict__ out) {
    out[OUTQ] = (float)(1.25 * loss_acc[0] / (double)OUTQ);
}

/* ---- fallback index->float (vq_main path only) ---- */
__global__ void vq_idxf(const int* __restrict__ idx, float* __restrict__ out) {
    const int r = blockIdx.x * 256 + threadIdx.x;
    if (r < NROWS) out[OUTQ + 1 + r] = (float)idx[r];
}

extern "C" void kernel_launch(void* const* d_in, const int* in_sizes, int n_in,
                              void* d_out, int out_size, void* d_ws, size_t ws_size,
                              hipStream_t stream) {
    const float* latents = (const float*)d_in[0];
    const float* cb      = (const float*)d_in[1];
    float* out = (float*)d_out;
    char*  ws  = (char*)d_ws;

    double*   loss = (double*)(ws + OFF_LOSS);
    float*    w2f  = (float*)(ws + OFF_W2);
    int*      idx  = (int*)(ws + OFF_IDX);
    unsigned* gcnt = (unsigned*)(ws + OFF_GCNT);
    unsigned* done = (unsigned*)(ws + OFF_DONE);

    if (ws_size >= (size_t)MIN_WS) {
        float*              x2f   = (float*)(ws + OFF_X2);
        unsigned long long* pack  = (unsigned long long*)(ws + OFF_PACK);
        unsigned*           gminU = (unsigned*)(ws + OFF_GMINU);
        uint2*              list  = (uint2*)(ws + OFF_LIST);
        __bf16*             BT    = (__bf16*)(ws + OFF_BT);
        float*              X     = (float*)(ws + OFF_X);
        __bf16*             A     = (__bf16*)(ws + OFF_A);

        vq_cbprep<<<Kk, 256, 0, stream>>>(cb, w2f, BT, loss, gcnt, done);
        vq_prep_a<<<dim3(NROWS/64, 4), 256, 0, stream>>>(latents, X, A, pack, gminU);
        vq_x2<<<NROWS/4, 256, 0, stream>>>(X, x2f);
        vq_gemm<<<2048, 256, 0, stream>>>(A, BT, w2f, gcnt, list, gminU);
        vq_rescore<<<1024, 256, 0, stream>>>(X, cb, w2f, x2f, gminU, gcnt, list, pack);
        vq_pick<<<NROWS/256, 256, 0, stream>>>(pack, idx, out, loss, done);
        vq_gather<<<(Bb*(Dd/4)*Tt)/256, 256, 0, stream>>>(cb, idx, out);
    } else {
        hipMemsetAsync(ws, 0, 16, stream);
        vq_w2<<<4, 256, 0, stream>>>(cb, w2f);
        vq_main<<<NROWS/64, 512, 0, stream>>>(latents, cb, w2f, idx, loss);
        vq_idxf<<<(NROWS + 255)/256, 256, 0, stream>>>(idx, out);
        vq_gather<<<(Bb*(Dd/4)*Tt)/256, 256, 0, stream>>>(cb, idx, out);
        vq_finalize<<<1, 1, 0, stream>>>(loss, out);
    }
}